// Round 4
// baseline (150.466 us; speedup 1.0000x reference)
//
#include <hip/hip_runtime.h>
#include <math.h>

#define VOCAB   32000
#define BLTOT   128    // B*L
#define HTOT    64     // H = 8 heads * 8 hph
#define BLT     4      // bl rows accumulated per thread
#define VPB     320    // threads per block (5 waves)
#define VT      4      // vocab rows per thread
// grid: x = VOCAB/(VPB*VT) = 25, y = BLTOT/BLT = 32  -> 800 blocks

#define LOG2E   1.44269504088896340736f

typedef float v2f __attribute__((ext_vector_type(2)));

// packed fp32 (VOP3P): 2 lanes of work per issue slot
static __device__ __forceinline__ v2f pk_add(v2f a, v2f b) {
    v2f d;
    asm("v_pk_add_f32 %0, %1, %2" : "=v"(d) : "v"(a), "v"(b));
    return d;
}
static __device__ __forceinline__ v2f pk_fma(v2f a, v2f b, v2f c) {
    asm("v_pk_fma_f32 %0, %1, %2, %0" : "+v"(c) : "v"(a), "v"(b));
    return c;
}

// ---------------------------------------------------------------------------
// Prep: 64 KB table in ws, per (bl, jj): [negfe4 | cw4]
//   negfe = -f * log2e ;  cw = amps * cos(phases - ip[j]) * W[j/8]
// ---------------------------------------------------------------------------
__global__ void prep_kernel(const float* __restrict__ freqs,
                            const float* __restrict__ amps,
                            const float* __restrict__ phases,
                            const float* __restrict__ ip,
                            const float* __restrict__ W,
                            float* __restrict__ ws) {
    int t = blockIdx.x * blockDim.x + threadIdx.x;   // 0 .. 8191
    if (t >= BLTOT * HTOT) return;
    int bl = t >> 6;
    int j  = t & 63;
    float negfe = -freqs[t] * LOG2E;
    float cw = amps[t] * cosf(phases[t] - ip[j]) * W[j >> 3];
    int jj = j >> 2, u = j & 3;
    float* base = ws + bl * 128 + jj * 8;
    base[u]     = negfe;
    base[4 + u] = cw;
}

// ---------------------------------------------------------------------------
// Main: thread owns VT=4 vocab rows x BLT=4 bl rows. Each LDS {negfe,cw}
// read now feeds VT*4 = 16 exp-terms (was 4 in R3) -> LDS pipe ~24k cy/CU,
// below the ~32k cy/CU quarter-rate v_exp floor. exp(-|f-v|) =
// exp2(-|v*log2e + negfe|) with -abs folded as source modifier.
// ---------------------------------------------------------------------------
__global__ __launch_bounds__(VPB, 4) void
wave_main(const float* __restrict__ vp,     // vocab_patterns, VOCAB x 64
          const float* __restrict__ uni,    // ws table
          const float* __restrict__ bptr,   // bias (1 elem)
          float* __restrict__ out) {        // (B*L, VOCAB)
    const int v0  = blockIdx.x * (VPB * VT) + threadIdx.x;
    const int bl0 = blockIdx.y * BLT;

    __shared__ float4 smem[BLT * 16 * 2];   // 2 KB: [negfe4|cw4] per (bl,jj)
    if (threadIdx.x < BLT * 16 * 2)
        smem[threadIdx.x] = ((const float4*)(uni + bl0 * 128))[threadIdx.x];
    __syncthreads();

    const float4* __restrict__ vp4 = (const float4*)vp;

    v2f acc01[BLT][VT], acc23[BLT][VT];
#pragma unroll
    for (int i = 0; i < BLT; ++i)
#pragma unroll
        for (int k = 0; k < VT; ++k) { acc01[i][k] = (v2f)(0.0f); acc23[i][k] = (v2f)(0.0f); }

#pragma unroll 2
    for (int jj = 0; jj < 16; ++jj) {
        v2f ve01[VT], ve23[VT];
#pragma unroll
        for (int k = 0; k < VT; ++k) {
            const float4 vf = vp4[(v0 + k * VPB) * 16 + jj];
            ve01[k].x = vf.x * LOG2E; ve01[k].y = vf.y * LOG2E;
            ve23[k].x = vf.z * LOG2E; ve23[k].y = vf.w * LOG2E;
        }
#pragma unroll
        for (int i = 0; i < BLT; ++i) {
            const float4 f4 = smem[(i * 16 + jj) * 2];       // negfe, broadcast
            const float4 c4 = smem[(i * 16 + jj) * 2 + 1];   // cw,    broadcast
            const v2f f01 = {f4.x, f4.y}, f23 = {f4.z, f4.w};
            const v2f c01 = {c4.x, c4.y}, c23 = {c4.z, c4.w};
#pragma unroll
            for (int k = 0; k < VT; ++k) {
                v2f d01 = pk_add(f01, ve01[k]);
                v2f d23 = pk_add(f23, ve23[k]);
                v2f e01, e23;
                e01.x = __builtin_amdgcn_exp2f(-__builtin_fabsf(d01.x));
                e01.y = __builtin_amdgcn_exp2f(-__builtin_fabsf(d01.y));
                e23.x = __builtin_amdgcn_exp2f(-__builtin_fabsf(d23.x));
                e23.y = __builtin_amdgcn_exp2f(-__builtin_fabsf(d23.y));
                acc01[i][k] = pk_fma(c01, e01, acc01[i][k]);
                acc23[i][k] = pk_fma(c23, e23, acc23[i][k]);
            }
        }
    }

    const float b0 = bptr[0];
#pragma unroll
    for (int i = 0; i < BLT; ++i)
#pragma unroll
        for (int k = 0; k < VT; ++k) {
            float s = (acc01[i][k].x + acc01[i][k].y) + (acc23[i][k].x + acc23[i][k].y);
            out[(bl0 + i) * VOCAB + v0 + k * VPB] = s + b0;   // coalesced per k
        }
}

extern "C" void kernel_launch(void* const* d_in, const int* in_sizes, int n_in,
                              void* d_out, int out_size, void* d_ws, size_t ws_size,
                              hipStream_t stream) {
    const float* freqs  = (const float*)d_in[0];
    const float* amps   = (const float*)d_in[1];
    const float* phases = (const float*)d_in[2];
    const float* vp     = (const float*)d_in[3];
    const float* ip     = (const float*)d_in[4];
    const float* W      = (const float*)d_in[5];
    const float* b      = (const float*)d_in[6];
    float* out = (float*)d_out;
    float* ws  = (float*)d_ws;   // needs 64 KB

    prep_kernel<<<dim3(32), dim3(256), 0, stream>>>(freqs, amps, phases, ip, W, ws);

    wave_main<<<dim3(VOCAB / (VPB * VT), BLTOT / BLT), dim3(VPB), 0, stream>>>(vp, ws, b, out);
}